// Round 1
// baseline (104.164 us; speedup 1.0000x reference)
//
#include <hip/hip_runtime.h>
#include <cstdint>

// LEVEL_SIZES = {256,128,64,32,16}, B=16, N=64 boxes, C=8, img 1024x1024
#define NBOX 64
#define NB   16
#define NC   8
#define EPSF 1e-8f
#define LN2F 0.69314718055994531f

// Cross-kernel scratch lives in module-scope device memory, NOT d_ws.
// Every slot is rewritten by k_scan before k_final reads it (same stream),
// so no state persists across calls. This removes all d_ws usage.
__device__ float4 g_partials[1664];

// grid layout (1664 blocks):
//   L0 [0,1024):    16*8 maps x 8 tiles of 8192 px   (Hl=256)
//   L1 [1024,1280): 16*8 maps x 2 tiles of 8192 px   (Hl=128)
//   L2 [1280,1408): 16*8 maps x 1 tile  of 4096 px   (Hl=64)
//   L3 [1408,1536): 16*8 maps x 1 tile  of 1024 px   (Hl=32)
//   L4 [1536,1664): 16*8 maps x 1 tile  of  256 px   (Hl=16)

__device__ __forceinline__ unsigned long long range_mask(int a, int e, int base) {
    int lo = a - base; lo = lo < 0 ? 0 : (lo > 64 ? 64 : lo);
    int hi = e - base; hi = hi < 0 ? 0 : (hi > 64 ? 64 : hi);
    if (hi <= lo) return 0ULL;
    unsigned long long hm = (hi >= 64) ? ~0ULL : ((1ULL << hi) - 1ULL);
    unsigned long long lm = (1ULL << lo) - 1ULL;
    return hm & ~lm;
}

struct SharedBuf {
    int rx1[NBOX], rx2[NBOX], ry1[NBOX], ry2[NBOX];
    unsigned long long rowm[128];    // flat [NROWS][W64], NROWS*W64 <= 128 at every level
    float red[4][4];
};

template<int LVL>
__device__ __forceinline__ void scan_level(
    SharedBuf& sh, int rel, int bid,
    const float* __restrict__ attn, const float* __restrict__ bboxs,
    float w, float h, int alpha, int beta)
{
    constexpr int Hl    = 256 >> LVL;
    constexpr int P     = Hl * Hl;
    constexpr int TPX   = (P < 8192) ? P : 8192;   // pixels per tile
    constexpr int NT    = P / TPX;                 // tiles per (b,c)
    constexpr int NROWS = TPX / Hl;                // rows per tile (16..64)
    constexpr int LOGW  = 8 - LVL;
    constexpr int W64   = (Hl >= 64) ? (Hl / 64) : 1;
    constexpr int NBATCH = (TPX + 1023) / 1024;    // float4 batches per thread (<=8)

    const int tile = (NT == 1) ? 0 : (rel % NT);
    const int bc   = (NT == 1) ? rel : (rel / NT);
    const int c = bc & 7, b = bc >> 3;
    const int tid = threadIdx.x;
    const int start = tile * TPX;
    const int r0    = tile * NROWS;

    // ---- 1) issue ALL attn loads first; latency hides under mask work ----
    const float* p = attn + (size_t)(b * NC + c) * P + start;
    float4 v[NBATCH];
#pragma unroll
    for (int k = 0; k < NBATCH; ++k) {
        int off = k * 1024 + tid * 4;
        if (off < TPX) v[k] = *(const float4*)(p + off);
    }

    // ---- 2) rects (wave 0) + rowm zero, overlapped with loads in flight ----
    if (tid < NROWS * W64) sh.rowm[tid] = 0ULL;
    if (tid < NBOX) {
        const float side  = (float)(1 << (LVL + alpha));
        const float min_a = side * side;
        const float sbb   = side * (float)beta;
        const float max_a = sbb * sbb;
        const float sx = (float)Hl / w;
        const float sy = (float)Hl / h;
        float4 bb = *(const float4*)(bboxs + (size_t)(b * NBOX + tid) * 4);
        bool valid = (bb.x <= w) && (bb.y <= h) && (bb.z <= w) && (bb.w <= h);
        float area = fabsf((bb.z - bb.x) * (bb.w - bb.y));
        bool sel = valid && (area >= min_a) && (area <= max_a);
        sh.rx1[tid] = (int)fmaxf(floorf(bb.x * sx), 0.f);
        sh.rx2[tid] = (int)fminf(ceilf(bb.z * sx) + 1.f, (float)Hl);
        int yi1 = (int)fmaxf(floorf(bb.y * sy), 0.f);
        int yi2 = (int)fminf(ceilf(bb.w * sy) + 1.f, (float)Hl);
        sh.ry1[tid] = sel ? yi1 : 0;
        sh.ry2[tid] = sel ? yi2 : 0;   // empty range when not selected
    }
    __syncthreads();

    // ---- 3) mask build, 4 waves x 16 boxes each, ds_or combine ----
    {
        const int g = tid >> 6;        // wave id
        const int r = tid & 63;
        if (r < NROWS) {
            const int hh = r0 + r;
            unsigned long long m[W64];
#pragma unroll
            for (int wi = 0; wi < W64; ++wi) m[wi] = 0ULL;
            const int n0 = g * 16;
            for (int n = n0; n < n0 + 16; ++n) {
                if (hh >= sh.ry1[n] && hh < sh.ry2[n]) {
                    int a = sh.rx1[n], e = sh.rx2[n];
#pragma unroll
                    for (int wi = 0; wi < W64; ++wi) m[wi] |= range_mask(a, e, wi * 64);
                }
            }
#pragma unroll
            for (int wi = 0; wi < W64; ++wi)
                if (m[wi]) atomicOr(&sh.rowm[r * W64 + wi], m[wi]);
        }
    }
    __syncthreads();

    // ---- 4) t-count rides on row popcounts ----
    float my_t = 0.f;
    if (tid < NROWS) {
#pragma unroll
        for (int wi = 0; wi < W64; ++wi)
            my_t += (float)__popcll(sh.rowm[tid * W64 + wi]);
    }

    // ---- 5) consume loads: 2 rotating accumulator sets (VGPR-lean, chain-split) ----
    float l2s[2], psA[2], ptA[2];
    l2s[0] = l2s[1] = psA[0] = psA[1] = ptA[0] = ptA[1] = 0.f;
#pragma unroll
    for (int k = 0; k < NBATCH; ++k) {
        int off = k * 1024 + tid * 4;
        if (off < TPX) {
            int s = k & 1;
            int hr = off >> LOGW;              // local row in tile
            int ww = off & (Hl - 1);
            unsigned long long wd = sh.rowm[hr * W64 + ((W64 == 1) ? 0 : (ww >> 6))];
            unsigned int bits = (unsigned int)(wd >> (ww & 63)) & 0xFu;
            float4 vv = v[k];
            { float pv = vv.x; bool t = bits & 1u; l2s[s] -= __log2f(t ? pv : 1.f - pv); psA[s] += pv; if (t) ptA[s] += pv; }
            { float pv = vv.y; bool t = bits & 2u; l2s[s] -= __log2f(t ? pv : 1.f - pv); psA[s] += pv; if (t) ptA[s] += pv; }
            { float pv = vv.z; bool t = bits & 4u; l2s[s] -= __log2f(t ? pv : 1.f - pv); psA[s] += pv; if (t) ptA[s] += pv; }
            { float pv = vv.w; bool t = bits & 8u; l2s[s] -= __log2f(t ? pv : 1.f - pv); psA[s] += pv; if (t) ptA[s] += pv; }
        }
    }
    float bce = l2s[0] + l2s[1];
    float psum = psA[0] + psA[1];
    float ptsum = ptA[0] + ptA[1];

    // ---- 6) wave + block reduce; private slot write (no atomics) ----
    for (int off = 32; off > 0; off >>= 1) {
        bce   += __shfl_down(bce,   off, 64);
        psum  += __shfl_down(psum,  off, 64);
        ptsum += __shfl_down(ptsum, off, 64);
        my_t  += __shfl_down(my_t,  off, 64);
    }
    if ((tid & 63) == 0) {
        int wv = tid >> 6;
        sh.red[wv][0] = bce; sh.red[wv][1] = psum; sh.red[wv][2] = ptsum; sh.red[wv][3] = my_t;
    }
    __syncthreads();
    if (tid == 0) {
        float4 o;
        o.x = (sh.red[0][0] + sh.red[1][0] + sh.red[2][0] + sh.red[3][0]) * LN2F;
        o.y =  sh.red[0][1] + sh.red[1][1] + sh.red[2][1] + sh.red[3][1];
        o.z =  sh.red[0][2] + sh.red[1][2] + sh.red[2][2] + sh.red[3][2];
        o.w =  sh.red[0][3] + sh.red[1][3] + sh.red[2][3] + sh.red[3][3];
        g_partials[bid] = o;
    }
}

__global__ __launch_bounds__(256)
void k_scan(const float* __restrict__ a0, const float* __restrict__ a1,
            const float* __restrict__ a2, const float* __restrict__ a3,
            const float* __restrict__ a4,
            const float* __restrict__ bboxs,
            const int* __restrict__ ih_p, const int* __restrict__ iw_p,
            const int* __restrict__ alpha_p, const int* __restrict__ beta_p) {
    __shared__ SharedBuf sh;
    const float w = (float)iw_p[0], h = (float)ih_p[0];
    const int alpha = alpha_p[0], beta = beta_p[0];
    const int bid = blockIdx.x;
    if      (bid < 1024) scan_level<0>(sh, bid,        bid, a0, bboxs, w, h, alpha, beta);
    else if (bid < 1280) scan_level<1>(sh, bid - 1024, bid, a1, bboxs, w, h, alpha, beta);
    else if (bid < 1408) scan_level<2>(sh, bid - 1280, bid, a2, bboxs, w, h, alpha, beta);
    else if (bid < 1536) scan_level<3>(sh, bid - 1408, bid, a3, bboxs, w, h, alpha, beta);
    else                 scan_level<4>(sh, bid - 1536, bid, a4, bboxs, w, h, alpha, beta);
}

__global__ void k_final(const float* __restrict__ bboxs,
                        const int* __restrict__ ih_p, const int* __restrict__ iw_p,
                        float* __restrict__ out) {
    const int tid = threadIdx.x;   // 256 threads
    __shared__ float pimg[NB];
    const float w = (float)iw_p[0], h = (float)ih_p[0];
    if (tid < NB) pimg[tid] = 0.f;
    __syncthreads();
    const int ntl[5]  = {8, 2, 1, 1, 1};
    const int base[5] = {0, 1024, 1280, 1408, 1536};
    for (int combo = tid; combo < 640; combo += 256) {
        int l  = combo >> 7;           // level
        int bc = combo & 127;          // b*8 + c
        int cnt = ntl[l];
        const float4* s0 = g_partials + base[l] + bc * cnt;
        float sb = 0.f, sp = 0.f, st = 0.f, sc = 0.f;
        for (int t = 0; t < cnt; ++t) {
            float4 x = s0[t];
            sb += x.x; sp += x.y; st += x.z; sc += x.w;
        }
        int HH = 256 >> l;
        float invP = 1.f / (float)(HH * HH);
        float dice = 1.f - (2.f * st + EPSF) / (sp + sc + EPSF);
        atomicAdd(&pimg[bc >> 3], 0.5f * sb * invP + 0.5f * dice);
    }
    __syncthreads();
    if (tid < NB) {
        const int b = tid;
        bool has = false;
        const float* bb = bboxs + (size_t)b * NBOX * 4;
        for (int n = 0; n < NBOX; ++n) {
            float x1 = bb[n * 4 + 0], y1 = bb[n * 4 + 1];
            float x2 = bb[n * 4 + 2], y2 = bb[n * 4 + 3];
            if (x1 <= w && y1 <= h && x2 <= w && y2 <= h) { has = true; break; }
        }
        pimg[b] = has ? pimg[b] * (1.f / 40.f) : 0.f;
    }
    __syncthreads();
    if (tid == 0) {
        float t = 0.f;
        for (int i = 0; i < NB; ++i) t += pimg[i];
        out[0] = t * (1.f / (float)NB);
    }
}

extern "C" void kernel_launch(void* const* d_in, const int* in_sizes, int n_in,
                              void* d_out, int out_size, void* d_ws, size_t ws_size,
                              hipStream_t stream) {
    const float* a0 = (const float*)d_in[0];
    const float* a1 = (const float*)d_in[1];
    const float* a2 = (const float*)d_in[2];
    const float* a3 = (const float*)d_in[3];
    const float* a4 = (const float*)d_in[4];
    const float* bboxs = (const float*)d_in[5];
    const int* ih = (const int*)d_in[6];
    const int* iw = (const int*)d_in[7];
    const int* al = (const int*)d_in[8];
    const int* be = (const int*)d_in[9];

    (void)d_ws; (void)ws_size;  // d_ws intentionally unused: partials live in g_partials

    k_scan<<<1664, 256, 0, stream>>>(a0, a1, a2, a3, a4, bboxs, ih, iw, al, be);
    k_final<<<1, 256, 0, stream>>>(bboxs, ih, iw, (float*)d_out);
}